// Round 17
// baseline (34.473 us; speedup 1.0000x reference)
//
#include <hip/hip_runtime.h>
#include <hip/hip_bf16.h>

#define MM 4096
#define NN 512
#define RR 32

__device__ __forceinline__ float softplus_f(float x) {
    return x > 20.0f ? x : log1pf(__expf(x));
}

__device__ __forceinline__ int bitrev6(int l) {
    return ((l & 1) << 5) | ((l & 2) << 3) | ((l & 4) << 1) |
           ((l & 8) >> 1) | ((l & 16) >> 3) | ((l & 32) >> 5);
}

// In-register 64-point DIF FFT across the 64 lanes of a wave.
__device__ __forceinline__ void wave_fft64(float& xr, float& xi) {
#pragma unroll
    for (int s = 32; s >= 1; s >>= 1) {
        const float pr = __shfl_xor(xr, s, 64);
        const float pi = __shfl_xor(xi, s, 64);
        const int   lane = threadIdx.x & 63;
        const bool  hi = (lane & s) != 0;
        const float ur = xr + pr, ui = xi + pi;
        const float vr = pr - xr, vi = pi - xi;
        const int   j  = lane & (s - 1);
        const float rev = (float)j * (1.0f / (float)(2 * s));   // [0, 0.5)
        const float ct = __builtin_amdgcn_cosf(rev);
        const float st = __builtin_amdgcn_sinf(rev);
        const float wr = fmaf(vr, ct,   vi * st);   // v * (ct - i st)
        const float wi = fmaf(vi, ct, -(vr * st));
        xr = hi ? wr : ur;
        xi = hi ? wi : ui;
    }
}

// ---------------------------------------------------------------------------
// FFT step 1 (proven): FFT-64 over n2, twiddle, transposed store.
// ---------------------------------------------------------------------------
__global__ __launch_bounds__(256) void fft64_step1(const float* __restrict__ H,
                                                   float2* __restrict__ zbuf) {
    const int wave = (blockIdx.x * 256 + threadIdx.x) >> 6;   // 0..2047
    const int lane = threadIdx.x & 63;                        // n2
    const int d    = wave >> 6;                               // 0..31
    const int n1   = wave & 63;                               // 0..63
    float xr = softplus_f(H[(size_t)d * MM + n1 + 64 * lane]);
    float xi = 0.0f;
    wave_fft64(xr, xi);
    const int k2 = bitrev6(lane);
    const float rev = (float)(n1 * k2) * (1.0f / 4096.0f);    // [0,1)
    const float ct = __builtin_amdgcn_cosf(rev);
    const float st = __builtin_amdgcn_sinf(rev);
    zbuf[(size_t)d * MM + k2 * 64 + n1] =
        make_float2(fmaf(xr, ct, xi * st), fmaf(xi, ct, -(xr * st)));
}

// ---------------------------------------------------------------------------
// FFT step 2 (proven): FFT-64 over n1 (contiguous), scatter.
// ---------------------------------------------------------------------------
__global__ __launch_bounds__(256) void fft64_step2(const float2* __restrict__ zbuf,
                                                   float2* __restrict__ hft) {
    const int wave = (blockIdx.x * 256 + threadIdx.x) >> 6;
    const int lane = threadIdx.x & 63;                        // n1
    const int d    = wave >> 6;
    const int k2   = wave & 63;
    const float2 z = zbuf[(size_t)d * MM + k2 * 64 + lane];
    float xr = z.x, xi = z.y;
    wave_fft64(xr, xi);
    hft[(size_t)d * MM + k2 + 64 * bitrev6(lane)] = make_float2(xr, xi);
}

// ---------------------------------------------------------------------------
// Main kernel — N-IN-LANES / WAVE-UNIFORM-H redesign:
//   lane = n  =>  h[d][m] is wave-uniform -> uniform (scalar-path) loads,
//   ZERO per-lane h traffic; per-m phasor advance is a 4-FMA rotation
//   (zero trans in the m loop). Params read from LDS transposed [d][n]
//   (lane-consecutive -> conflict-free).
// Block 512 thr = 8 waves: wid = {msub (4) x dhalf (2)}; 64 n x 64 m-half.
// Each wave: 16 d x 16 m, phasor recurrence over m, acc in registers.
// d-halves merged + transposed through LDS so global writes are m-major
// (lane=n direct stores would be stride-4096 scatter — fatal).
// Grid (2048/64, 512/64) = (32, 8) = 256 blocks (1/CU), LDS 49.5 KB.
// Math formulas identical to the R6/R8/R14-proven Hermitian body.
// ---------------------------------------------------------------------------
__global__ __launch_bounds__(512, 2) void shiftnmf_real(const float* __restrict__ W,
                                                        const float* __restrict__ tau,
                                                        const float2* __restrict__ hft,
                                                        float* __restrict__ out) {
    __shared__ float A_s[RR][64];      // 8 KB  [d][n]
    __shared__ float tf_s[RR][64];     // 8 KB
    __shared__ float ru_s[RR][64];     // 8 KB
    __shared__ float iu_s[RR][64];     // 8 KB
    __shared__ float h2048_s[RR];
    __shared__ float tile[64][65];     // 16.6 KB transpose buffer (padded)

    const int tid = threadIdx.x;
    const int mb  = blockIdx.x * 64;       // [0, 2048)
    const int nb  = blockIdx.y * 64;

    // params: 64 n x 32 d = 2048 entries, 4 per thread
#pragma unroll
    for (int j = 0; j < 4; ++j) {
        const int e = tid + 512 * j;       // [0, 2048)
        const int n = e & 63;
        const int d = e >> 6;
        const float w = W[(size_t)(nb + n) * RR + d];
        const float t = tau[(size_t)(nb + n) * RR + d];
        A_s[d][n]  = softplus_f(w);
        tf_s[d][n] = t * (1.0f / (float)MM);
        const float fr = t - floorf(t);                 // frac(tau)
        ru_s[d][n] =  __builtin_amdgcn_cosf(fr);        // Re e^{-2pi i tau}
        iu_s[d][n] = -__builtin_amdgcn_sinf(fr);        // Im e^{-2pi i tau}
    }
    if (tid < RR) h2048_s[tid] = hft[(size_t)tid * MM + 2048].x;
    __syncthreads();

    const int lane = tid & 63;             // n-local
    const int wid  = tid >> 6;             // 0..7
    const int msub = wid & 3;              // m sub-tile
    const int dh   = wid >> 2;             // d half: 0 or 1
    const int m0   = mb + msub * 16;
    const float m0f = (float)m0;

    float accm[16], accp[16];
#pragma unroll
    for (int j = 0; j < 16; ++j) { accm[j] = 0.0f; accp[j] = 0.0f; }

    // h double-buffer (uniform loads: address has NO lane dependence)
    float4 hbA[8], hbB[8];
    {
        const float4* hr = (const float4*)(hft + (size_t)(dh * 16) * MM + m0);
#pragma unroll
        for (int q = 0; q < 8; ++q) hbA[q] = hr[q];
    }

#pragma unroll 2
    for (int i = 0; i < 16; ++i) {
        const int d = dh * 16 + i;
        // prefetch next d's h row into the other buffer
        const int dnx = (i < 15) ? d + 1 : d;
        const float4* hrn = (const float4*)(hft + (size_t)dnx * MM + m0);
        float4* nxt = (i & 1) ? hbA : hbB;
        const float4* cur = (i & 1) ? hbB : hbA;
#pragma unroll
        for (int q = 0; q < 8; ++q) nxt[q] = hrn[q];

        const float A  = A_s[d][lane];
        const float tf = tf_s[d][lane];
        const float ru = ru_s[d][lane];
        const float iu = iu_s[d][lane];

        float r0 = tf * m0f;  r0 -= floorf(r0);        // [0,1)
        const float c0 = __builtin_amdgcn_cosf(r0);
        const float s0 = __builtin_amdgcn_sinf(r0);
        float dl = tf - floorf(tf);                    // 1-m-step rotator
        const float cd = __builtin_amdgcn_cosf(dl);
        const float sd = __builtin_amdgcn_sinf(dl);
        float ca = A * c0, sa = A * s0;                // phasor at m0

#pragma unroll
        for (int j = 0; j < 16; ++j) {
            const float hx = (j & 1) ? cur[j >> 1].z : cur[j >> 1].x;
            const float hy = (j & 1) ? cur[j >> 1].w : cur[j >> 1].y;
            const float rz = fmaf(ca, hx,   sa * hy);
            const float iz = fmaf(ca, hy, -(sa * hx));
            accm[j] += rz;
            accp[j]  = fmaf(ru, rz, fmaf(iu, iz, accp[j]));
            if (j < 15) {
                const float can = fmaf(ca, cd, -(sa * sd));
                const float san = fmaf(sa, cd,  (ca * sd));
                ca = can; sa = san;
            }
        }
    }

    // ---- merge d-halves + transpose + coalesced write: accm pass ----
    if (dh == 1) {
#pragma unroll
        for (int j = 0; j < 16; ++j) tile[lane][msub * 16 + j] = accm[j];
    }
    __syncthreads();
    if (dh == 0) {
#pragma unroll
        for (int j = 0; j < 16; ++j) tile[lane][msub * 16 + j] += accm[j];
    }
    __syncthreads();
    {
        const int row = tid >> 3;              // 0..63 (n-local)
        const int c0_ = (tid & 7) * 8;         // col base
        float* orow = out + (size_t)(nb + row) * MM + mb;
#pragma unroll
        for (int j = 0; j < 8; ++j) orow[c0_ + j] = tile[row][c0_ + j];
    }
    __syncthreads();

    // ---- accp (Hermitian mirror) pass ----
    if (dh == 1) {
#pragma unroll
        for (int j = 0; j < 16; ++j) tile[lane][msub * 16 + j] = accp[j];
    }
    __syncthreads();
    if (dh == 0) {
#pragma unroll
        for (int j = 0; j < 16; ++j) tile[lane][msub * 16 + j] += accp[j];
    }
    __syncthreads();
    {
        const int row = tid >> 3;
        const int c0_ = (tid & 7) * 8;
        float* orow = out + (size_t)(nb + row) * MM;
#pragma unroll
        for (int j = 0; j < 8; ++j) {
            const int m = mb + c0_ + j;        // [0, 2047]
            if (m != 0) orow[MM - m] = tile[row][c0_ + j];   // [2049, 4095]
        }
    }

    // Nyquist column m = 2048 (real bin): wave 0 of bx==0 blocks, lane = n.
    if (blockIdx.x == 0 && wid == 0) {
        float acc = 0.0f;
        for (int d = 0; d < RR; ++d) {
            float r = tf_s[d][lane] * 2048.0f;
            r -= floorf(r);
            acc = fmaf(A_s[d][lane] * h2048_s[d], __builtin_amdgcn_cosf(r), acc);
        }
        out[(size_t)(nb + lane) * MM + 2048] = acc;
    }
}

// ---------------------------------------------------------------------------
// Complex-output hedge path (never taken in practice): R5-proven kernel.
// ---------------------------------------------------------------------------
__global__ __launch_bounds__(256) void shiftnmf_cplx(const float* __restrict__ W,
                                                     const float* __restrict__ tau,
                                                     const float2* __restrict__ hft,
                                                     float* __restrict__ out) {
    __shared__ float spw_s[16][RR];
    __shared__ float tau_s[16][RR];
    const int tid = threadIdx.x;
    const int mb  = blockIdx.x * 256;
    const int nb  = blockIdx.y * 16;
    for (int idx = tid; idx < 16 * RR; idx += 256) {
        const int nl = idx >> 5;
        const int dd = idx & 31;
        spw_s[nl][dd] = softplus_f(W[(size_t)(nb + nl) * RR + dd]);
        tau_s[nl][dd] = tau[(size_t)(nb + nl) * RR + dd] * (1.0f / (float)MM);
    }
    __syncthreads();
    const int g  = tid >> 5;
    const int ml = tid & 31;
    const int n0 = g * 2;
    const float m0f = (float)(mb + ml);
    const float2* hcol = hft + mb + ml;
    float accR[2][8], accI[2][8];
#pragma unroll
    for (int j = 0; j < 2; ++j)
#pragma unroll
        for (int k = 0; k < 8; ++k) { accR[j][k] = 0.0f; accI[j][k] = 0.0f; }
    float2 hc[8], hn[8];
#pragma unroll
    for (int k = 0; k < 8; ++k) hc[k] = hcol[32 * k];
    for (int d = 0; d < RR; ++d) {
        const float2* hnp = hcol + (size_t)((d + 1 < RR) ? d + 1 : d) * MM;
#pragma unroll
        for (int k = 0; k < 8; ++k) hn[k] = hnp[32 * k];
#pragma unroll
        for (int j = 0; j < 2; ++j) {
            const float A  = spw_s[n0 + j][d];
            const float tf = tau_s[n0 + j][d];
            float r0 = tf * m0f;  r0 -= floorf(r0);
            float dl = tf * 32.0f; dl -= floorf(dl);
            const float c0 = __builtin_amdgcn_cosf(r0);
            const float s0 = __builtin_amdgcn_sinf(r0);
            const float cd = __builtin_amdgcn_cosf(dl);
            const float sd = __builtin_amdgcn_sinf(dl);
            float ca = A * c0, sa = A * s0;
            float cb = ca * cd - sa * sd;
            float sb = sa * cd + ca * sd;
            const float c2 = fmaf(-2.0f * sd, sd, 1.0f);
            const float s2 = 2.0f * sd * cd;
#pragma unroll
            for (int t4 = 0; t4 < 4; ++t4) {
                const float2 h0 = hc[2 * t4];
                const float2 h1 = hc[2 * t4 + 1];
                accR[j][2*t4]   = fmaf(ca, h0.x, fmaf(sa, h0.y, accR[j][2*t4]));
                accR[j][2*t4+1] = fmaf(cb, h1.x, fmaf(sb, h1.y, accR[j][2*t4+1]));
                accI[j][2*t4]   = fmaf(ca, h0.y, fmaf(-sa, h0.x, accI[j][2*t4]));
                accI[j][2*t4+1] = fmaf(cb, h1.y, fmaf(-sb, h1.x, accI[j][2*t4+1]));
                if (t4 < 3) {
                    const float can = fmaf(ca, c2, -(sa * s2));
                    const float san = fmaf(sa, c2,  (ca * s2));
                    const float cbn = fmaf(cb, c2, -(sb * s2));
                    const float sbn = fmaf(sb, c2,  (cb * s2));
                    ca = can; sa = san; cb = cbn; sb = sbn;
                }
            }
        }
#pragma unroll
        for (int k = 0; k < 8; ++k) hc[k] = hn[k];
    }
#pragma unroll
    for (int j = 0; j < 2; ++j) {
        float2* orow = (float2*)out + (size_t)(nb + n0 + j) * MM + mb + ml;
#pragma unroll
        for (int k = 0; k < 8; ++k)
            orow[32 * k] = make_float2(accR[j][k], accI[j][k]);
    }
}

extern "C" void kernel_launch(void* const* d_in, const int* in_sizes, int n_in,
                              void* d_out, int out_size, void* d_ws, size_t ws_size,
                              hipStream_t stream) {
    const float* W   = (const float*)d_in[0];   // (512, 32)
    const float* H   = (const float*)d_in[1];   // (32, 4096)
    const float* tau = (const float*)d_in[2];   // (512, 32)

    const size_t hft_bytes = (size_t)RR * MM * sizeof(float2);  // 1 MB
    if (ws_size < 2 * hft_bytes) return;        // safe bail (no crash)
    float2* zbuf = (float2*)d_ws;               // step-1 intermediate (1 MB)
    float2* hft  = zbuf + (size_t)RR * MM;      // spectrum (1 MB)

    fft64_step1<<<512, 256, 0, stream>>>(H, zbuf);
    fft64_step2<<<512, 256, 0, stream>>>(zbuf, hft);

    if (out_size >= 2 * NN * MM) {
        dim3 grid(MM / 256, NN / 16);
        shiftnmf_cplx<<<grid, 256, 0, stream>>>(W, tau, hft, (float*)d_out);
    } else {
        dim3 grid(2048 / 64, NN / 64);
        shiftnmf_real<<<grid, 512, 0, stream>>>(W, tau, hft, (float*)d_out);
    }
}

// Round 18
// 28.679 us; speedup vs baseline: 1.2020x; 1.2020x over previous
//
#include <hip/hip_runtime.h>
#include <hip/hip_bf16.h>

#define MM 4096
#define NN 512
#define RR 32

__device__ __forceinline__ float softplus_f(float x) {
    return x > 20.0f ? x : log1pf(__expf(x));
}

__device__ __forceinline__ int bitrev6(int l) {
    return ((l & 1) << 5) | ((l & 2) << 3) | ((l & 4) << 1) |
           ((l & 8) >> 1) | ((l & 16) >> 3) | ((l & 32) >> 5);
}

// In-register 64-point DIF FFT across the 64 lanes of a wave.
__device__ __forceinline__ void wave_fft64(float& xr, float& xi) {
#pragma unroll
    for (int s = 32; s >= 1; s >>= 1) {
        const float pr = __shfl_xor(xr, s, 64);
        const float pi = __shfl_xor(xi, s, 64);
        const int   lane = threadIdx.x & 63;
        const bool  hi = (lane & s) != 0;
        const float ur = xr + pr, ui = xi + pi;
        const float vr = pr - xr, vi = pi - xi;
        const int   j  = lane & (s - 1);
        const float rev = (float)j * (1.0f / (float)(2 * s));   // [0, 0.5)
        const float ct = __builtin_amdgcn_cosf(rev);
        const float st = __builtin_amdgcn_sinf(rev);
        const float wr = fmaf(vr, ct,   vi * st);   // v * (ct - i st)
        const float wi = fmaf(vi, ct, -(vr * st));
        xr = hi ? wr : ur;
        xi = hi ? wi : ui;
    }
}

// ---------------------------------------------------------------------------
// FFT step 1 (proven): FFT-64 over n2, twiddle, transposed store.
// ---------------------------------------------------------------------------
__global__ __launch_bounds__(256) void fft64_step1(const float* __restrict__ H,
                                                   float2* __restrict__ zbuf) {
    const int wave = (blockIdx.x * 256 + threadIdx.x) >> 6;   // 0..2047
    const int lane = threadIdx.x & 63;                        // n2
    const int d    = wave >> 6;                               // 0..31
    const int n1   = wave & 63;                               // 0..63
    float xr = softplus_f(H[(size_t)d * MM + n1 + 64 * lane]);
    float xi = 0.0f;
    wave_fft64(xr, xi);
    const int k2 = bitrev6(lane);
    const float rev = (float)(n1 * k2) * (1.0f / 4096.0f);    // [0,1)
    const float ct = __builtin_amdgcn_cosf(rev);
    const float st = __builtin_amdgcn_sinf(rev);
    zbuf[(size_t)d * MM + k2 * 64 + n1] =
        make_float2(fmaf(xr, ct, xi * st), fmaf(xi, ct, -(xr * st)));
}

// ---------------------------------------------------------------------------
// FFT step 2 (proven): FFT-64 over n1 (contiguous), scatter.
// ---------------------------------------------------------------------------
__global__ __launch_bounds__(256) void fft64_step2(const float2* __restrict__ zbuf,
                                                   float2* __restrict__ hft) {
    const int wave = (blockIdx.x * 256 + threadIdx.x) >> 6;
    const int lane = threadIdx.x & 63;                        // n1
    const int d    = wave >> 6;
    const int k2   = wave & 63;
    const float2 z = zbuf[(size_t)d * MM + k2 * 64 + lane];
    float xr = z.x, xi = z.y;
    wave_fft64(xr, xi);
    hft[(size_t)d * MM + k2 + 64 * bitrev6(lane)] = make_float2(xr, xi);
}

// ---------------------------------------------------------------------------
// Main kernel — REVERT to the best-measured variant (R14, 29.0 µs):
//   htile[RR][64] float4 (32 KB), params packed as one float4 per (row,d),
//   K=4 consecutive m per thread (2 contiguous ds_read_b128), Hermitian
//   pairing. Block 512 thr = 16 rows x 32 lanes; grid (16, 32) = 512 blocks;
//   LDS 40.1 KB -> 2 blocks/CU = 16 waves/CU.
// Ledger: 8 structural variants (occupancy 2-8 w/SIMD, LDS 2-8 insts,
// banks, ILP, trans 0.25-2/out, uniform-h) all land main in 19.5-24 µs;
// this combination is the empirical optimum.
// ---------------------------------------------------------------------------
__global__ __launch_bounds__(512, 2) void shiftnmf_real(const float* __restrict__ W,
                                                        const float* __restrict__ tau,
                                                        const float2* __restrict__ hft,
                                                        float* __restrict__ out) {
    __shared__ float4 htile[RR][64];    // 32 KB: Hft[d][mb..mb+128) as float4
    __shared__ float4 pw_s[16][RR];     // 8 KB: (A, tf, ru, iu) per (row, d)
    __shared__ float  h2048_s[RR];

    const int tid = threadIdx.x;
    const int mb  = blockIdx.x * 128;      // [0, 2048)
    const int nb  = blockIdx.y * 16;

    {   // per-(row,d) params: 512 threads cover 16 x 32 exactly
        const int nl = tid >> 5;
        const int dd = tid & 31;
        const float w = W[(size_t)(nb + nl) * RR + dd];
        const float t = tau[(size_t)(nb + nl) * RR + dd];
        const float tf = t * (1.0f / (float)MM);
        const float fr = t - floorf(t);                        // frac(tau)
        pw_s[nl][dd] = make_float4(softplus_f(w), tf,
                                   __builtin_amdgcn_cosf(fr),   // ru
                                   -__builtin_amdgcn_sinf(fr)); // iu
    }
    {   // stage Hft tile: 32 rows x 64 float4 = 2048 float4, 4 per thread
        float4* hf4 = &htile[0][0];
#pragma unroll
        for (int j = 0; j < 4; ++j) {
            const int idx = tid + 512 * j;          // [0, 2048)
            const int r   = idx >> 6;               // d row 0..31
            const int c   = idx & 63;               // float4 col 0..63
            hf4[idx] = ((const float4*)(hft + (size_t)r * MM + mb))[c];
        }
    }
    if (tid < RR) h2048_s[tid] = hft[(size_t)tid * MM + 2048].x;
    __syncthreads();

    const int g  = tid >> 5;                // row 0..15
    const int ml = tid & 31;
    const int n  = nb + g;
    const int m0 = mb + 4 * ml;             // [0, 2044], multiple of 4
    const float m0f = (float)m0;

    float accm[4] = {0.f, 0.f, 0.f, 0.f};
    float accp[4] = {0.f, 0.f, 0.f, 0.f};

#pragma unroll 2
    for (int d = 0; d < RR; ++d) {
        const float4 P = pw_s[g][d];        // 1 x ds_read_b128
        const float A  = P.x;
        const float tf = P.y;
        const float ru = P.z;
        const float iu = P.w;

        float r0 = tf * m0f;  r0 -= floorf(r0);        // [0,1)
        const float c0 = __builtin_amdgcn_cosf(r0);
        const float s0 = __builtin_amdgcn_sinf(r0);
        float dl = tf - floorf(tf);                    // per-1-m rotator
        const float cd = __builtin_amdgcn_cosf(dl);
        const float sd = __builtin_amdgcn_sinf(dl);
        float ca = A * c0, sa = A * s0;                // phasor at m0

        const float4 q0 = htile[d][2 * ml];            // h[m0], h[m0+1]
        const float4 q1 = htile[d][2 * ml + 1];        // h[m0+2], h[m0+3]

#define PAIR(K, HX, HY)                                                     \
        {                                                                   \
            const float rz = fmaf(ca, HX,   sa * HY);                       \
            const float iz = fmaf(ca, HY, -(sa * HX));                      \
            accm[K] += rz;                                                  \
            accp[K]  = fmaf(ru, rz, fmaf(iu, iz, accp[K]));                 \
        }
#define ROT()                                                               \
        {                                                                   \
            const float can = fmaf(ca, cd, -(sa * sd));                     \
            const float san = fmaf(sa, cd,  (ca * sd));                     \
            ca = can; sa = san;                                             \
        }
        PAIR(0, q0.x, q0.y) ROT()
        PAIR(1, q0.z, q0.w) ROT()
        PAIR(2, q1.x, q1.y) ROT()
        PAIR(3, q1.z, q1.w)
#undef PAIR
#undef ROT
    }

    float* orow = out + (size_t)n * MM;
    // m-side: aligned float4 store
    *(float4*)(orow + m0) = make_float4(accm[0], accm[1], accm[2], accm[3]);
    // Hermitian side: scalar stores (reversed, contiguous across lanes)
    if (m0 != 0) {
#pragma unroll
        for (int k = 0; k < 4; ++k) orow[MM - (m0 + k)] = accp[k];
    } else {
#pragma unroll
        for (int k = 1; k < 4; ++k) orow[MM - k] = accp[k];   // skip m=0 pair
    }

    // Nyquist column m = 2048 (real bin): one lane per row, bx==0 blocks.
    if (blockIdx.x == 0 && ml == 0) {
        float acc = 0.0f;
        for (int d = 0; d < RR; ++d) {
            const float4 P = pw_s[g][d];
            float r = P.y * 2048.0f;
            r -= floorf(r);
            acc = fmaf(P.x * h2048_s[d], __builtin_amdgcn_cosf(r), acc);
        }
        orow[2048] = acc;
    }
}

// ---------------------------------------------------------------------------
// Complex-output hedge path (never taken in practice): R5-proven kernel.
// ---------------------------------------------------------------------------
__global__ __launch_bounds__(256) void shiftnmf_cplx(const float* __restrict__ W,
                                                     const float* __restrict__ tau,
                                                     const float2* __restrict__ hft,
                                                     float* __restrict__ out) {
    __shared__ float spw_s[16][RR];
    __shared__ float tau_s[16][RR];
    const int tid = threadIdx.x;
    const int mb  = blockIdx.x * 256;
    const int nb  = blockIdx.y * 16;
    for (int idx = tid; idx < 16 * RR; idx += 256) {
        const int nl = idx >> 5;
        const int dd = idx & 31;
        spw_s[nl][dd] = softplus_f(W[(size_t)(nb + nl) * RR + dd]);
        tau_s[nl][dd] = tau[(size_t)(nb + nl) * RR + dd] * (1.0f / (float)MM);
    }
    __syncthreads();
    const int g  = tid >> 5;
    const int ml = tid & 31;
    const int n0 = g * 2;
    const float m0f = (float)(mb + ml);
    const float2* hcol = hft + mb + ml;
    float accR[2][8], accI[2][8];
#pragma unroll
    for (int j = 0; j < 2; ++j)
#pragma unroll
        for (int k = 0; k < 8; ++k) { accR[j][k] = 0.0f; accI[j][k] = 0.0f; }
    float2 hc[8], hn[8];
#pragma unroll
    for (int k = 0; k < 8; ++k) hc[k] = hcol[32 * k];
    for (int d = 0; d < RR; ++d) {
        const float2* hnp = hcol + (size_t)((d + 1 < RR) ? d + 1 : d) * MM;
#pragma unroll
        for (int k = 0; k < 8; ++k) hn[k] = hnp[32 * k];
#pragma unroll
        for (int j = 0; j < 2; ++j) {
            const float A  = spw_s[n0 + j][d];
            const float tf = tau_s[n0 + j][d];
            float r0 = tf * m0f;  r0 -= floorf(r0);
            float dl = tf * 32.0f; dl -= floorf(dl);
            const float c0 = __builtin_amdgcn_cosf(r0);
            const float s0 = __builtin_amdgcn_sinf(r0);
            const float cd = __builtin_amdgcn_cosf(dl);
            const float sd = __builtin_amdgcn_sinf(dl);
            float ca = A * c0, sa = A * s0;
            float cb = ca * cd - sa * sd;
            float sb = sa * cd + ca * sd;
            const float c2 = fmaf(-2.0f * sd, sd, 1.0f);
            const float s2 = 2.0f * sd * cd;
#pragma unroll
            for (int t4 = 0; t4 < 4; ++t4) {
                const float2 h0 = hc[2 * t4];
                const float2 h1 = hc[2 * t4 + 1];
                accR[j][2*t4]   = fmaf(ca, h0.x, fmaf(sa, h0.y, accR[j][2*t4]));
                accR[j][2*t4+1] = fmaf(cb, h1.x, fmaf(sb, h1.y, accR[j][2*t4+1]));
                accI[j][2*t4]   = fmaf(ca, h0.y, fmaf(-sa, h0.x, accI[j][2*t4]));
                accI[j][2*t4+1] = fmaf(cb, h1.y, fmaf(-sb, h1.x, accI[j][2*t4+1]));
                if (t4 < 3) {
                    const float can = fmaf(ca, c2, -(sa * s2));
                    const float san = fmaf(sa, c2,  (ca * s2));
                    const float cbn = fmaf(cb, c2, -(sb * s2));
                    const float sbn = fmaf(sb, c2,  (cb * s2));
                    ca = can; sa = san; cb = cbn; sb = sbn;
                }
            }
        }
#pragma unroll
        for (int k = 0; k < 8; ++k) hc[k] = hn[k];
    }
#pragma unroll
    for (int j = 0; j < 2; ++j) {
        float2* orow = (float2*)out + (size_t)(nb + n0 + j) * MM + mb + ml;
#pragma unroll
        for (int k = 0; k < 8; ++k)
            orow[32 * k] = make_float2(accR[j][k], accI[j][k]);
    }
}

extern "C" void kernel_launch(void* const* d_in, const int* in_sizes, int n_in,
                              void* d_out, int out_size, void* d_ws, size_t ws_size,
                              hipStream_t stream) {
    const float* W   = (const float*)d_in[0];   // (512, 32)
    const float* H   = (const float*)d_in[1];   // (32, 4096)
    const float* tau = (const float*)d_in[2];   // (512, 32)

    const size_t hft_bytes = (size_t)RR * MM * sizeof(float2);  // 1 MB
    if (ws_size < 2 * hft_bytes) return;        // safe bail (no crash)
    float2* zbuf = (float2*)d_ws;               // step-1 intermediate (1 MB)
    float2* hft  = zbuf + (size_t)RR * MM;      // spectrum (1 MB)

    fft64_step1<<<512, 256, 0, stream>>>(H, zbuf);
    fft64_step2<<<512, 256, 0, stream>>>(zbuf, hft);

    if (out_size >= 2 * NN * MM) {
        dim3 grid(MM / 256, NN / 16);
        shiftnmf_cplx<<<grid, 256, 0, stream>>>(W, tau, hft, (float*)d_out);
    } else {
        dim3 grid(2048 / 128, NN / 16);
        shiftnmf_real<<<grid, 512, 0, stream>>>(W, tau, hft, (float*)d_out);
    }
}